// Round 1
// baseline (289.576 us; speedup 1.0000x reference)
//
#include <hip/hip_runtime.h>
#include <hip/hip_fp16.h>

// CommNet critic forward, fully fused: 1 workgroup = 1 batch (32 agents).
// All GEMMs via v_mfma_f32_16x16x32_f16 (fp32 accumulate). B=2048,A=32,D=128,H=256.

#define NB   2048
#define NA   32
#define DIN  128
#define HID  256
#define SA   264   // f16 row stride for activation LDS tiles (+8 pad -> even bank spread)

typedef _Float16 half8  __attribute__((ext_vector_type(8)));
typedef float    float4v __attribute__((ext_vector_type(4)));

// f16 weight-fragment arena layout in d_ws (element offsets)
#define ENC_OFF    0
#define FOBS_OFF   32768
#define WIH_OFF    98304
#define WHH_OFF    294912
#define PREP_TOTAL 491520   // f16 elements -> 983040 bytes needed in ws

// Pre-arrange weights into exact MFMA B-fragment order, f16:
// frag[((ks*NT + nt)*64 + lane)*8 + j] = W[nt*16 + lane%16][ks*32 + (lane/16)*8 + j]
__global__ void prep_weights(const float* __restrict__ encW, const float* __restrict__ fobsW,
                             const float* __restrict__ wih,  const float* __restrict__ whh,
                             _Float16* __restrict__ prep) {
    int F = blockIdx.x * 256 + threadIdx.x;
    if (F >= PREP_TOTAL) return;
    const float* src; int K, NT, local = F;
    if (F < FOBS_OFF)     { src = encW;  K = 128; NT = 16; }
    else if (F < WIH_OFF) { src = fobsW; K = 256; NT = 16; local = F - FOBS_OFF; }
    else if (F < WHH_OFF) { src = wih;   K = 256; NT = 48; local = F - WIH_OFF; }
    else                  { src = whh;   K = 256; NT = 48; local = F - WHH_OFF; }
    int j    = local & 7;
    int lane = (local >> 3) & 63;
    int t    = local >> 9;
    int nt   = t % NT;
    int ks   = t / NT;
    int col  = nt * 16 + (lane & 15);
    int k    = ks * 32 + ((lane >> 4) << 3) + j;
    prep[F] = (_Float16)src[col * K + k];
}

__device__ __forceinline__ float sigmoid_f(float x) {
    x = fminf(fmaxf(x, -30.f), 30.f);
    return 1.f / (1.f + __expf(-x));
}
__device__ __forceinline__ float tanh_f(float x) {
    x = fminf(fmaxf(x, -15.f), 15.f);
    float e = __expf(-2.f * x);
    return (1.f - e) / (1.f + e);
}

__device__ __forceinline__ void zero22(float4v a[2][2]) {
    float4v z = {0.f, 0.f, 0.f, 0.f};
    a[0][0] = z; a[0][1] = z; a[1][0] = z; a[1][1] = z;
}

// One wave computes D-tiles (mt in {0,1}) x (ntg0, ntg0+1): out[32 x 32cols] of a GEMM
// A from LDS (f16, stride SA), B from prepped global fragments (or raw fp32 fallback).
template<int KSTEPS>
__device__ __forceinline__ void gemm_tile(const _Float16* __restrict__ Abuf,
        const _Float16* __restrict__ prepm, int NT, int ntg0,
        const float* __restrict__ raw, int K, int use_prep,
        int lane, float4v acc[2][2])
{
    const int l16 = lane & 15;
    const int kq  = (lane >> 4) << 3;
    #pragma unroll
    for (int ks = 0; ks < KSTEPS; ks++) {
        int kbase = ks * 32 + kq;
        half8 a0 = *(const half8*)(Abuf + l16 * SA + kbase);
        half8 a1 = *(const half8*)(Abuf + (16 + l16) * SA + kbase);
        half8 b0, b1;
        if (use_prep) {
            b0 = *(const half8*)(prepm + (((ks * NT + ntg0    ) * 64 + lane) << 3));
            b1 = *(const half8*)(prepm + (((ks * NT + ntg0 + 1) * 64 + lane) << 3));
        } else {
            #pragma unroll
            for (int j = 0; j < 8; j++) {
                b0[j] = (_Float16)raw[(ntg0 * 16 + l16) * K + kbase + j];
                b1[j] = (_Float16)raw[((ntg0 + 1) * 16 + l16) * K + kbase + j];
            }
        }
        acc[0][0] = __builtin_amdgcn_mfma_f32_16x16x32_f16(a0, b0, acc[0][0], 0, 0, 0);
        acc[0][1] = __builtin_amdgcn_mfma_f32_16x16x32_f16(a0, b1, acc[0][1], 0, 0, 0);
        acc[1][0] = __builtin_amdgcn_mfma_f32_16x16x32_f16(a1, b0, acc[1][0], 0, 0, 0);
        acc[1][1] = __builtin_amdgcn_mfma_f32_16x16x32_f16(a1, b1, acc[1][1], 0, 0, 0);
    }
}

__global__ __launch_bounds__(512) void commnet_fused(
    const float* __restrict__ obs, const _Float16* __restrict__ prep,
    const float* __restrict__ enc_b, const float* __restrict__ fobs_b,
    const float* __restrict__ b_ih, const float* __restrict__ b_hh,
    const float* __restrict__ dec_W, const float* __restrict__ dec_b,
    float* __restrict__ out,
    const float* __restrict__ encW, const float* __restrict__ fobsW,
    const float* __restrict__ wih, const float* __restrict__ whh,
    int use_prep)
{
    const int b    = blockIdx.x;
    const int tid  = threadIdx.x;
    const int lane = tid & 63;
    const int w    = tid >> 6;     // wave 0..7
    const int l16  = lane & 15;
    const int quad = lane >> 4;
    const int ntl0 = w * 2;        // this wave's local ntile pair within 256 cols

    __shared__ __align__(16) _Float16 sA[3][NA * SA];
    __shared__ float S[HID];

    // ---- stage obs (fp32 global -> f16 LDS), zero S
    const float* obsb = obs + (size_t)b * NA * DIN;
    for (int i = tid; i < NA * DIN; i += 512) {
        int r = i >> 7, k = i & 127;
        sA[0][r * SA + k] = (_Float16)obsb[i];
    }
    if (tid < HID) S[tid] = 0.f;
    __syncthreads();

    float4v acc[2][2];

    // ---- encoder: e = relu(obs @ encW^T + enc_b) -> sA[1]
    zero22(acc);
    gemm_tile<4>(&sA[0][0], prep + ENC_OFF, 16, ntl0, encW, DIN, use_prep, lane, acc);
    #pragma unroll
    for (int nn = 0; nn < 2; nn++) {
        int col = (ntl0 + nn) * 16 + l16;
        float bb = enc_b[col];
        #pragma unroll
        for (int mt = 0; mt < 2; mt++)
            #pragma unroll
            for (int r = 0; r < 4; r++) {
                int row = mt * 16 + quad * 4 + r;
                float v = acc[mt][nn][r] + bb;
                sA[1][row * SA + col] = (_Float16)fmaxf(v, 0.f);
            }
    }
    __syncthreads();

    // ---- fobs: h = e @ fobsW^T + fobs_b -> sA[0]
    zero22(acc);
    gemm_tile<8>(&sA[1][0], prep + FOBS_OFF, 16, ntl0, fobsW, HID, use_prep, lane, acc);
    #pragma unroll
    for (int nn = 0; nn < 2; nn++) {
        int col = (ntl0 + nn) * 16 + l16;
        float bb = fobs_b[col];
        #pragma unroll
        for (int mt = 0; mt < 2; mt++)
            #pragma unroll
            for (int r = 0; r < 4; r++) {
                int row = mt * 16 + quad * 4 + r;
                sA[0][row * SA + col] = (_Float16)(acc[mt][nn][r] + bb);
            }
    }
    __syncthreads();

    // ---- GRU1 (x=0 so gi = b_ih). A = sA[0] (h). gates r(0), n(2), z(1)
    float rn[2][2][4];
    zero22(acc);
    gemm_tile<8>(&sA[0][0], prep + WHH_OFF, 48, 0 + ntl0, whh, HID, use_prep, lane, acc);
    #pragma unroll
    for (int nn = 0; nn < 2; nn++) {
        int col = (ntl0 + nn) * 16 + l16;
        float bi = b_ih[col], bh = b_hh[col];
        #pragma unroll
        for (int mt = 0; mt < 2; mt++)
            #pragma unroll
            for (int r = 0; r < 4; r++)
                rn[mt][nn][r] = sigmoid_f(bi + acc[mt][nn][r] + bh);
    }
    zero22(acc);
    gemm_tile<8>(&sA[0][0], prep + WHH_OFF, 48, 32 + ntl0, whh, HID, use_prep, lane, acc);
    #pragma unroll
    for (int nn = 0; nn < 2; nn++) {
        int col = (ntl0 + nn) * 16 + l16;
        float bi = b_ih[512 + col], bh = b_hh[512 + col];
        #pragma unroll
        for (int mt = 0; mt < 2; mt++)
            #pragma unroll
            for (int r = 0; r < 4; r++)
                rn[mt][nn][r] = tanh_f(bi + rn[mt][nn][r] * (acc[mt][nn][r] + bh));
    }
    zero22(acc);
    gemm_tile<8>(&sA[0][0], prep + WHH_OFF, 48, 16 + ntl0, whh, HID, use_prep, lane, acc);
    #pragma unroll
    for (int nn = 0; nn < 2; nn++) {
        int col = (ntl0 + nn) * 16 + l16;
        float bi = b_ih[256 + col], bh = b_hh[256 + col];
        float ssum = 0.f;
        #pragma unroll
        for (int mt = 0; mt < 2; mt++)
            #pragma unroll
            for (int r = 0; r < 4; r++) {
                int row = mt * 16 + quad * 4 + r;
                float z = sigmoid_f(bi + acc[mt][nn][r] + bh);
                float hold = (float)sA[0][row * SA + col];
                float h1 = (1.f - z) * rn[mt][nn][r] + z * hold;
                sA[1][row * SA + col] = (_Float16)h1;   // h1 -> sA[1]
                ssum += h1;
            }
        atomicAdd(&S[col], ssum);
    }
    __syncthreads();

    // ---- comm: c = (colsum - h1)/32 -> sA[2]
    for (int i = tid; i < NA * HID; i += 512) {
        int r = i >> 8, k = i & 255;
        float hv = (float)sA[1][r * SA + k];
        sA[2][r * SA + k] = (_Float16)((S[k] - hv) * (1.f / 32.f));
    }
    __syncthreads();
    if (tid < NA) S[tid] = 0.f;   // reuse S[0..31] as decoder row accumulators
    __syncthreads();

    // ---- GRU2: gi from c (sA[2]) @ W_ih, gh from h1 (sA[1]) @ W_hh
    float4v acci[2][2], acch[2][2];
    zero22(acci); zero22(acch);
    gemm_tile<8>(&sA[2][0], prep + WIH_OFF, 48, 0 + ntl0, wih, HID, use_prep, lane, acci);
    gemm_tile<8>(&sA[1][0], prep + WHH_OFF, 48, 0 + ntl0, whh, HID, use_prep, lane, acch);
    #pragma unroll
    for (int nn = 0; nn < 2; nn++) {
        int col = (ntl0 + nn) * 16 + l16;
        float bi = b_ih[col], bh = b_hh[col];
        #pragma unroll
        for (int mt = 0; mt < 2; mt++)
            #pragma unroll
            for (int r = 0; r < 4; r++)
                rn[mt][nn][r] = sigmoid_f(acci[mt][nn][r] + bi + acch[mt][nn][r] + bh);
    }
    zero22(acci); zero22(acch);
    gemm_tile<8>(&sA[2][0], prep + WIH_OFF, 48, 32 + ntl0, wih, HID, use_prep, lane, acci);
    gemm_tile<8>(&sA[1][0], prep + WHH_OFF, 48, 32 + ntl0, whh, HID, use_prep, lane, acch);
    #pragma unroll
    for (int nn = 0; nn < 2; nn++) {
        int col = (ntl0 + nn) * 16 + l16;
        float bi = b_ih[512 + col], bh = b_hh[512 + col];
        #pragma unroll
        for (int mt = 0; mt < 2; mt++)
            #pragma unroll
            for (int r = 0; r < 4; r++)
                rn[mt][nn][r] = tanh_f((acci[mt][nn][r] + bi) + rn[mt][nn][r] * (acch[mt][nn][r] + bh));
    }
    zero22(acci); zero22(acch);
    gemm_tile<8>(&sA[2][0], prep + WIH_OFF, 48, 16 + ntl0, wih, HID, use_prep, lane, acci);
    gemm_tile<8>(&sA[1][0], prep + WHH_OFF, 48, 16 + ntl0, whh, HID, use_prep, lane, acch);
    #pragma unroll
    for (int nn = 0; nn < 2; nn++) {
        int col = (ntl0 + nn) * 16 + l16;
        float bi = b_ih[256 + col], bh = b_hh[256 + col];
        #pragma unroll
        for (int mt = 0; mt < 2; mt++)
            #pragma unroll
            for (int r = 0; r < 4; r++) {
                int row = mt * 16 + quad * 4 + r;
                float z = sigmoid_f(acci[mt][nn][r] + bi + acch[mt][nn][r] + bh);
                float h1v = (float)sA[1][row * SA + col];
                rn[mt][nn][r] = (1.f - z) * rn[mt][nn][r] + z * h1v;   // h2 in regs
            }
    }

    // ---- decoder: out[row] = sum_col h2*dec_W[col] + dec_b
    float dw0 = dec_W[(ntl0    ) * 16 + l16];
    float dw1 = dec_W[(ntl0 + 1) * 16 + l16];
    float p[2][4];
    #pragma unroll
    for (int mt = 0; mt < 2; mt++)
        #pragma unroll
        for (int r = 0; r < 4; r++)
            p[mt][r] = rn[mt][0][r] * dw0 + rn[mt][1][r] * dw1;
    #pragma unroll
    for (int m = 1; m <= 8; m <<= 1) {
        #pragma unroll
        for (int mt = 0; mt < 2; mt++)
            #pragma unroll
            for (int r = 0; r < 4; r++)
                p[mt][r] += __shfl_xor(p[mt][r], m);
    }
    if (l16 == 0) {
        #pragma unroll
        for (int mt = 0; mt < 2; mt++)
            #pragma unroll
            for (int r = 0; r < 4; r++)
                atomicAdd(&S[mt * 16 + quad * 4 + r], p[mt][r]);
    }
    __syncthreads();
    if (tid < NA) out[(size_t)b * NA + tid] = S[tid] + dec_b[0];
}

extern "C" void kernel_launch(void* const* d_in, const int* in_sizes, int n_in,
                              void* d_out, int out_size, void* d_ws, size_t ws_size,
                              hipStream_t stream) {
    const float* obs   = (const float*)d_in[0];
    // d_in[1] (act) is unused by the reference
    const float* encW  = (const float*)d_in[2];
    const float* encb  = (const float*)d_in[3];
    const float* fobsW = (const float*)d_in[4];
    const float* fobsb = (const float*)d_in[5];
    const float* wih   = (const float*)d_in[6];
    const float* bih   = (const float*)d_in[7];
    const float* whh   = (const float*)d_in[8];
    const float* bhh   = (const float*)d_in[9];
    const float* decW  = (const float*)d_in[10];
    const float* decb  = (const float*)d_in[11];
    float* out = (float*)d_out;

    _Float16* prep = (_Float16*)d_ws;
    int use_prep = (ws_size >= (size_t)PREP_TOTAL * sizeof(_Float16)) ? 1 : 0;
    if (use_prep) {
        prep_weights<<<(PREP_TOTAL + 255) / 256, 256, 0, stream>>>(encW, fobsW, wih, whh, prep);
    }
    commnet_fused<<<NB, 512, 0, stream>>>(obs, prep, encb, fobsb, bih, bhh, decW, decb, out,
                                          encW, fobsW, wih, whh, use_prep);
}